// Round 1
// baseline (1612.224 us; speedup 1.0000x reference)
//
#include <hip/hip_runtime.h>
#include <hip/hip_bf16.h>
#include <math.h>

// Problem constants (fixed by the reference)
#define N      4096          // N_HID == N_TH == N_TP
#define KSTEPS 8
#define NF     16384         // feature length for W3 (nH + nP + 2*maxL)

// ---------------------------------------------------------------------------
// Weighted column sum:  out[j] += sum_{i in slice} w[i] * M[i][j]
// grid = (4, 128), block = 256.  Each thread owns 4 consecutive columns
// (float4); each blockIdx.y owns a 32-row slice; atomics combine slices.
// out must be pre-zeroed.
// ---------------------------------------------------------------------------
__global__ void colsum_kernel(const float* __restrict__ M,
                              const float* __restrict__ w,
                              float* __restrict__ out,
                              int rowsPerSlice) {
    int c4 = blockIdx.x * blockDim.x + threadIdx.x;      // float4 column idx [0,1024)
    int i0 = blockIdx.y * rowsPerSlice;
    float4 acc = make_float4(0.f, 0.f, 0.f, 0.f);
    for (int i = i0; i < i0 + rowsPerSlice; ++i) {
        float wi = w[i];
        float4 m = ((const float4*)(M + (size_t)i * N))[c4];
        acc.x += wi * m.x;
        acc.y += wi * m.y;
        acc.z += wi * m.z;
        acc.w += wi * m.w;
    }
    atomicAdd(&out[c4 * 4 + 0], acc.x);
    atomicAdd(&out[c4 * 4 + 1], acc.y);
    atomicAdd(&out[c4 * 4 + 2], acc.z);
    atomicAdd(&out[c4 * 4 + 3], acc.w);
}

// ---------------------------------------------------------------------------
// u[row] = dot(W2[row, :], sk).  One block (256 thr) per row.
// Also zeroes bufv[row] so the following colsum can accumulate atomically.
// ---------------------------------------------------------------------------
__global__ void rowdot_u_kernel(const float* __restrict__ W2,
                                const float* __restrict__ sk,
                                float* __restrict__ u,
                                float* __restrict__ bufv) {
    int row = blockIdx.x;
    const float4* r = (const float4*)(W2 + (size_t)row * N);
    const float4* x = (const float4*)sk;
    float acc = 0.f;
    for (int c = threadIdx.x; c < N / 4; c += blockDim.x) {
        float4 a = r[c];
        float4 b = x[c];
        acc += a.x * b.x + a.y * b.y + a.z * b.z + a.w * b.w;
    }
    __shared__ float red[256];
    red[threadIdx.x] = acc;
    __syncthreads();
    for (int s = 128; s > 0; s >>= 1) {
        if (threadIdx.x < s) red[threadIdx.x] += red[threadIdx.x + s];
        __syncthreads();
    }
    if (threadIdx.x == 0) {
        u[row]    = red[0];
        bufv[row] = 0.f;     // pre-zero logits buffer for the next colsum
    }
}

// ---------------------------------------------------------------------------
// Single-block softmax over N entries: wgt = softmax(v).
// Optionally zeroes zbuf[0..N) (the xk accumulator for the next colsum).
// ---------------------------------------------------------------------------
__global__ void softmax_kernel(const float* __restrict__ v,
                               float* __restrict__ wgt,
                               float* __restrict__ zbuf) {
    __shared__ float red[1024];
    int tid = threadIdx.x;
    float m = -1e30f;
    for (int i = tid; i < N; i += 1024) m = fmaxf(m, v[i]);
    red[tid] = m;
    __syncthreads();
    for (int s = 512; s > 0; s >>= 1) {
        if (tid < s) red[tid] = fmaxf(red[tid], red[tid + s]);
        __syncthreads();
    }
    float mx = red[0];
    __syncthreads();
    float sum = 0.f;
    for (int i = tid; i < N; i += 1024) {
        float e = expf(v[i] - mx);
        wgt[i] = e;
        sum += e;
    }
    red[tid] = sum;
    __syncthreads();
    for (int s = 512; s > 0; s >>= 1) {
        if (tid < s) red[tid] += red[tid + s];
        __syncthreads();
    }
    float inv = 1.f / red[0];
    for (int i = tid; i < N; i += 1024) wgt[i] *= inv;
    if (zbuf) {
        for (int i = tid; i < N; i += 1024) zbuf[i] = 0.f;
    }
}

// ---------------------------------------------------------------------------
// Fused GRU cell: one block per hidden unit t.  Computes the 6 row-dots
// (i_r,i_z,i_n,h_r,h_z,h_n), applies gates, writes h_out[t].
// Blocks 0..2 also zero logits3 for the following feat reduction.
// ---------------------------------------------------------------------------
__global__ void gru_kernel(const float* __restrict__ w_ih,
                           const float* __restrict__ w_hh,
                           const float* __restrict__ xk,
                           const float* __restrict__ h,
                           float* __restrict__ h_out,
                           float* __restrict__ logits3) {
    int t = blockIdx.x;
    float acc[6] = {0.f, 0.f, 0.f, 0.f, 0.f, 0.f};
    const float4* xv = (const float4*)xk;
    const float4* hv = (const float4*)h;
    for (int g = 0; g < 3; ++g) {
        const float4* wi = (const float4*)(w_ih + (size_t)(g * N + t) * N);
        const float4* wh = (const float4*)(w_hh + (size_t)(g * N + t) * N);
        for (int c = threadIdx.x; c < N / 4; c += blockDim.x) {
            float4 a = wi[c], b = xv[c];
            acc[g] += a.x * b.x + a.y * b.y + a.z * b.z + a.w * b.w;
            float4 a2 = wh[c], b2 = hv[c];
            acc[3 + g] += a2.x * b2.x + a2.y * b2.y + a2.z * b2.z + a2.w * b2.w;
        }
    }
    __shared__ float red[6][256];
    for (int g = 0; g < 6; ++g) red[g][threadIdx.x] = acc[g];
    __syncthreads();
    for (int s = 128; s > 0; s >>= 1) {
        if (threadIdx.x < s)
            for (int g = 0; g < 6; ++g)
                red[g][threadIdx.x] += red[g][threadIdx.x + s];
        __syncthreads();
    }
    if (threadIdx.x == 0) {
        float ir = red[0][0], iz = red[1][0], in_ = red[2][0];
        float hr = red[3][0], hz = red[4][0], hn = red[5][0];
        float r = 1.f / (1.f + expf(-(ir + hr)));
        float z = 1.f / (1.f + expf(-(iz + hz)));
        float n = tanhf(in_ + r * hn);
        h_out[t] = (1.f - z) * n + z * h[t];
        if (t < 3) logits3[t] = 0.f;
    }
}

// ---------------------------------------------------------------------------
// logits3[l] += sum_f W3[f][l] * feat[f], feat built on the fly from
// (sk_new, xk).  grid = 64 blocks x 256 threads = exactly NF threads.
// ---------------------------------------------------------------------------
__global__ void feat_kernel(const float* __restrict__ W3,
                            const float* __restrict__ s,
                            const float* __restrict__ x,
                            float* __restrict__ logits3) {
    int f = blockIdx.x * blockDim.x + threadIdx.x;   // 0..16383
    int j = f & (N - 1);
    int seg = f >> 12;
    float sv = s[j], xv = x[j];
    float val;
    if (seg == 0)      val = sv;
    else if (seg == 1) val = xv;
    else if (seg == 2) val = fabsf(sv - xv);
    else               val = sv * xv;
    float l0 = val * W3[f * 3 + 0];
    float l1 = val * W3[f * 3 + 1];
    float l2 = val * W3[f * 3 + 2];

    __shared__ float red[3][256];
    red[0][threadIdx.x] = l0;
    red[1][threadIdx.x] = l1;
    red[2][threadIdx.x] = l2;
    __syncthreads();
    for (int st = 128; st > 0; st >>= 1) {
        if (threadIdx.x < st)
            for (int g = 0; g < 3; ++g)
                red[g][threadIdx.x] += red[g][threadIdx.x + st];
        __syncthreads();
    }
    if (threadIdx.x == 0) {
        atomicAdd(&logits3[0], red[0][0]);
        atomicAdd(&logits3[1], red[1][0]);
        atomicAdd(&logits3[2], red[2][0]);
    }
}

// ---------------------------------------------------------------------------
// P_r += softmax(logits3); on the final step write out = P_r / K.
// ---------------------------------------------------------------------------
__global__ void acc3_kernel(const float* __restrict__ l3,
                            float* __restrict__ Pr,
                            float* __restrict__ out,
                            int finalize) {
    if (threadIdx.x == 0 && blockIdx.x == 0) {
        float a = l3[0], b = l3[1], c = l3[2];
        float m = fmaxf(a, fmaxf(b, c));
        float e0 = expf(a - m), e1 = expf(b - m), e2 = expf(c - m);
        float s = e0 + e1 + e2;
        float p0 = Pr[0] + e0 / s;
        float p1 = Pr[1] + e1 / s;
        float p2 = Pr[2] + e2 / s;
        Pr[0] = p0; Pr[1] = p1; Pr[2] = p2;
        if (finalize) {
            out[0] = p0 / (float)KSTEPS;
            out[1] = p1 / (float)KSTEPS;
            out[2] = p2 / (float)KSTEPS;
        }
    }
}

extern "C" void kernel_launch(void* const* d_in, const int* in_sizes, int n_in,
                              void* d_out, int out_size, void* d_ws, size_t ws_size,
                              hipStream_t stream) {
    const float* M_h  = (const float*)d_in[0];
    const float* M_p  = (const float*)d_in[1];
    const float* w1   = (const float*)d_in[2];
    const float* W2   = (const float*)d_in[3];
    const float* W3   = (const float*)d_in[4];
    const float* w_ih = (const float*)d_in[5];
    const float* w_hh = (const float*)d_in[6];
    float* out = (float*)d_out;

    float* ws    = (float*)d_ws;
    float* buf_v = ws;            // 4096  logits scratch (v, beta-logits)
    float* buf_w = ws + 4096;     // 4096  softmax weights (alpha / beta)
    float* sk_a  = ws + 8192;     // 4096  hidden state ping
    float* sk_b  = ws + 12288;    // 4096  hidden state pong
    float* xk    = ws + 16384;    // 4096  GRU input vector
    float* u     = ws + 20480;    // 4096  W2 @ sk
    float* l3    = ws + 24576;    // 3     label logits
    float* Pr    = ws + 24579;    // 3     accumulated probabilities

    // zero the whole small scratch region (ws is poisoned to 0xAA)
    hipMemsetAsync(d_ws, 0, (size_t)24592 * sizeof(float), stream);

    dim3 csGrid(4, 128);

    // alpha = softmax(w1^T M_h);  sk0 = alpha @ M_h
    colsum_kernel<<<csGrid, 256, 0, stream>>>(M_h, w1, buf_v, 32);
    softmax_kernel<<<1, 1024, 0, stream>>>(buf_v, buf_w, nullptr);
    colsum_kernel<<<csGrid, 256, 0, stream>>>(M_h, buf_w, sk_a, 32);

    float* h  = sk_a;
    float* hn = sk_b;
    for (int k = 0; k < KSTEPS; ++k) {
        // beta-logits = (W2 @ h)^T @ M_p   (no 4096^3 GEMM needed)
        rowdot_u_kernel<<<4096, 256, 0, stream>>>(W2, h, u, buf_v);
        colsum_kernel<<<csGrid, 256, 0, stream>>>(M_p, u, buf_v, 32);
        softmax_kernel<<<1, 1024, 0, stream>>>(buf_v, buf_w, xk); // beta; zero xk
        // xk = beta @ M_p
        colsum_kernel<<<csGrid, 256, 0, stream>>>(M_p, buf_w, xk, 32);
        // h' = GRUCell(xk, h)
        gru_kernel<<<4096, 256, 0, stream>>>(w_ih, w_hh, xk, h, hn, l3);
        // P_r += softmax(W3^T feat(h', xk))
        feat_kernel<<<64, 256, 0, stream>>>(W3, hn, xk, l3);
        acc3_kernel<<<1, 64, 0, stream>>>(l3, Pr, out, k == KSTEPS - 1 ? 1 : 0);
        float* t = h; h = hn; hn = t;
    }
}